// Round 9
// baseline (188.536 us; speedup 1.0000x reference)
//
#include <hip/hip_runtime.h>
#include <math.h>

#define SEQ 4096
#define DIM 1024
#define DHEAD 256
#define NHEADS 4

typedef __attribute__((ext_vector_type(8))) short bf16x8;
typedef __attribute__((ext_vector_type(4))) float f32x4;
typedef __attribute__((ext_vector_type(16))) float f32x16;
typedef __attribute__((ext_vector_type(4))) short short4v;
typedef __attribute__((ext_vector_type(8))) short short8v;

// fp32 -> bf16 round-to-nearest-even, as raw ushort bits
__device__ __forceinline__ unsigned short f2b(float f) {
    union { float f; unsigned u; } v; v.f = f;
    unsigned r = v.u + 0x7FFFu + ((v.u >> 16) & 1u);
    return (unsigned short)(r >> 16);
}
__device__ __forceinline__ float b2f(unsigned short u) {
    union { unsigned u; float f; } v; v.u = ((unsigned)u) << 16;
    return v.f;
}

// async global->LDS, 16B per lane; lds = wave-uniform base, g is per-lane
__device__ __forceinline__ void gll16(const void* g, void* lds) {
    __builtin_amdgcn_global_load_lds(
        (const __attribute__((address_space(1))) unsigned*)g,
        (__attribute__((address_space(3))) unsigned*)lds, 16, 0, 0);
}

__device__ __forceinline__ f32x4 mfma16(bf16x8 a, bf16x8 b, f32x4 c) {
    return __builtin_amdgcn_mfma_f32_16x16x32_bf16(a, b, c, 0, 0, 0);
}
__device__ __forceinline__ f32x16 mfma32(bf16x8 a, bf16x8 b, f32x16 c) {
    return __builtin_amdgcn_mfma_f32_32x32x16_bf16(a, b, c, 0, 0, 0);
}

// ---------------------------------------------------------------------------
// convert fp32 -> bf16, n4 float4's
// ---------------------------------------------------------------------------
__global__ __launch_bounds__(256)
void conv_kernel(const float* __restrict__ in, unsigned short* __restrict__ out, int n4) {
    int i = blockIdx.x * 256 + threadIdx.x;
    if (i >= n4) return;
    float4 v = ((const float4*)in)[i];
    short4v o;
    o[0] = (short)f2b(v.x); o[1] = (short)f2b(v.y);
    o[2] = (short)f2b(v.z); o[3] = (short)f2b(v.w);
    *(short4v*)(out + (size_t)i * 4) = o;
}

// ---------------------------------------------------------------------------
// Wq [4][1024][256] fp32 -> WqT [4][256][1024] bf16
// ---------------------------------------------------------------------------
__global__ __launch_bounds__(256)
void wqt_kernel(const float* __restrict__ Wq, unsigned short* __restrict__ WqT) {
    __shared__ unsigned short T[64][72];
    const int tid = threadIdx.x;
    const int h = blockIdx.z;
    const int d0 = blockIdx.x * 64, c0 = blockIdx.y * 64;
#pragma unroll
    for (int it = 0; it < 4; ++it) {
        int f = tid + 256 * it;
        int row = f >> 4, cg = f & 15;
        float4 v = *(const float4*)&Wq[((size_t)(h * DIM + d0 + row)) * DHEAD + c0 + cg * 4];
        T[row][cg * 4 + 0] = f2b(v.x); T[row][cg * 4 + 1] = f2b(v.y);
        T[row][cg * 4 + 2] = f2b(v.z); T[row][cg * 4 + 3] = f2b(v.w);
    }
    __syncthreads();
#pragma unroll
    for (int it = 0; it < 2; ++it) {
        int f = tid + 256 * it;
        int cl = f >> 3, dg = f & 7;
        short8v o;
#pragma unroll
        for (int e = 0; e < 8; ++e) o[e] = (short)T[dg * 8 + e][cl];
        *(short8v*)&WqT[((size_t)(h * DHEAD + c0 + cl)) * DIM + d0 + dg * 8] = o;
    }
}

// ---------------------------------------------------------------------------
// qkv [4][4096][256] bf16 -> qkvT [4][256][4096] bf16
// ---------------------------------------------------------------------------
__global__ __launch_bounds__(256)
void qkvt_kernel(const unsigned short* __restrict__ qkv, unsigned short* __restrict__ qkvT) {
    __shared__ unsigned short T[64][72];
    const int tid = threadIdx.x;
    const int h = blockIdx.z;
    const int r0 = blockIdx.x * 64, c0 = blockIdx.y * 64;
#pragma unroll
    for (int it = 0; it < 2; ++it) {
        int f = tid + 256 * it;
        int row = f >> 3, cg = f & 7;
        short8v v = *(const short8v*)&qkv[((size_t)h * SEQ + r0 + row) * DHEAD + c0 + cg * 8];
#pragma unroll
        for (int e = 0; e < 8; ++e) T[row][cg * 8 + e] = (unsigned short)v[e];
    }
    __syncthreads();
#pragma unroll
    for (int it = 0; it < 2; ++it) {
        int f = tid + 256 * it;
        int cl = f >> 3, rg = f & 7;
        short8v o;
#pragma unroll
        for (int e = 0; e < 8; ++e) o[e] = (short)T[rg * 8 + e][cl];
        *(short8v*)&qkvT[((size_t)h * DHEAD + c0 + cl) * SEQ + r0 + rg * 8] = o;
    }
}

// ---------------------------------------------------------------------------
// K1: qkv = x @ Wq  (bf16 MFMA, BM=BN=128, BK=64, out: qkv bf16 [4][4096][256])
// ---------------------------------------------------------------------------
__global__ __launch_bounds__(256)
void qkv_gemm_kernel(const unsigned short* __restrict__ A,
                     const unsigned short* __restrict__ B,
                     unsigned short* __restrict__ qkv) {
    __shared__ unsigned short As[128 * 64];
    __shared__ unsigned short Bs[128 * 64];
    const int tid = threadIdx.x, w = tid >> 6, l = tid & 63;
    const int g = l >> 4, r16 = l & 15;
    const int m0 = blockIdx.x * 128, n0 = blockIdx.y * 128;
    const int wm = (w >> 1) * 64, wn = (w & 1) * 64;

    f32x4 acc[4][4];
#pragma unroll
    for (int mr = 0; mr < 4; ++mr)
#pragma unroll
        for (int nr = 0; nr < 4; ++nr) acc[mr][nr] = (f32x4){0.f, 0.f, 0.f, 0.f};

    for (int kb = 0; kb < DIM; kb += 64) {
        __syncthreads();
#pragma unroll
        for (int cc = 0; cc < 4; ++cc) {
            int row = w * 32 + cc * 8 + (l >> 3);
            int c = (l & 7) ^ (row & 7);
            gll16(&A[(size_t)(m0 + row) * DIM + kb + c * 8], &As[(size_t)(w * 32 + cc * 8) * 64]);
            gll16(&B[(size_t)(n0 + row) * DIM + kb + c * 8], &Bs[(size_t)(w * 32 + cc * 8) * 64]);
        }
        __syncthreads();
#pragma unroll
        for (int s = 0; s < 2; ++s) {
            bf16x8 af[4], bf[4];
#pragma unroll
            for (int mr = 0; mr < 4; ++mr) {
                int row = wm + mr * 16 + r16;
                int st = (s * 4 + g) ^ (row & 7);
                af[mr] = *(const bf16x8*)&As[row * 64 + st * 8];
            }
#pragma unroll
            for (int nr = 0; nr < 4; ++nr) {
                int row = wn + nr * 16 + r16;
                int st = (s * 4 + g) ^ (row & 7);
                bf[nr] = *(const bf16x8*)&Bs[row * 64 + st * 8];
            }
#pragma unroll
            for (int mr = 0; mr < 4; ++mr)
#pragma unroll
                for (int nr = 0; nr < 4; ++nr)
                    acc[mr][nr] = mfma16(af[mr], bf[nr], acc[mr][nr]);
        }
    }
#pragma unroll
    for (int mr = 0; mr < 4; ++mr)
#pragma unroll
        for (int nr = 0; nr < 4; ++nr) {
            int n = n0 + wn + nr * 16 + r16;
            int h = n >> 8, c = n & 255;
#pragma unroll
            for (int r = 0; r < 4; ++r) {
                int m = m0 + wm + mr * 16 + g * 4 + r;
                qkv[((size_t)h * SEQ + m) * DHEAD + c] = f2b(acc[mr][nr][r]);
            }
        }
}

// ---------------------------------------------------------------------------
// K2: MFMA flash attention with 32x32x16 MFMA (halves LDS bytes per FLOP).
// 512 thr / 8 waves, wave owns 32 q-rows end-to-end (QBLK=256).
// grid 192: qb = bid/12 (16 q-blocks), h = (bid%12)/3, third tt = bid%3
// (thirds of keys: 1408/1344/1344 -> NT = 44/42/42 tiles of KBLK=32).
// Swapped QK^T (mfma32(K,Q)): D col = lane&31 = q -> softmax AND rescale
// lane-local. P -> PV B-frags built in registers (f2b pack + shfl_xor(32)).
// K & V^T double-buffered (64KB LDS), R8's counted-vmcnt pipeline.
// ---------------------------------------------------------------------------
__global__ __launch_bounds__(512, 2)
void attn_kernel(const unsigned short* __restrict__ qkv,
                 const unsigned short* __restrict__ qkvT,
                 unsigned short* __restrict__ p0,
                 unsigned short* __restrict__ p1,
                 unsigned short* __restrict__ p2,
                 float* __restrict__ ml) {
    __shared__ unsigned short Ks[2][32 * 256];  // 2x16KB, row j: st16=(c&24)|((c&7)^(j&7))
    __shared__ unsigned short Vt[2][256 * 32];  // 2x16KB, row d: st16=c^(d&3)

    const int tid = threadIdx.x, w = tid >> 6, l = tid & 63;
    const int l31 = l & 31, hi = l >> 5;
    const int bid = blockIdx.x;
    const int qb = bid / 12, rem = bid % 12;
    const int h = rem / 3, tt = rem % 3;
    const int jb0 = (tt == 0) ? 0 : 1408 + (tt - 1) * 1344;
    const int NT = (tt == 0) ? 44 : 42;
    const unsigned short* __restrict__ qh = qkv + (size_t)h * SEQ * DHEAD;
    const unsigned short* __restrict__ qth = qkvT + (size_t)h * DHEAD * SEQ;

    // Q fragments (B-operand of 32x32x16): lane q = qrow, k = d = 16s + 8hi + e
    const int qrow = qb * 256 + w * 32 + l31;
    bf16x8 qf[16];
#pragma unroll
    for (int s = 0; s < 16; ++s)
        qf[s] = *(const bf16x8*)&qh[(size_t)qrow * DHEAD + s * 16 + hi * 8];

#define STAGE(buf, jb)                                                              \
    {                                                                               \
        _Pragma("unroll")                                                           \
        for (int cc = 0; cc < 2; ++cc) {                                            \
            int ch = w * 2 + cc;              /* 1KB chunk = 2 K-rows */            \
            int j = ch * 2 + (l >> 5);                                              \
            int cp = l & 31;                                                        \
            int c = (cp & 24) | ((cp & 7) ^ (j & 7));                               \
            gll16(&qh[(size_t)((jb) + j) * DHEAD + c * 8], &Ks[buf][(size_t)ch * 512]); \
        }                                                                           \
        _Pragma("unroll")                                                           \
        for (int cc = 0; cc < 2; ++cc) {                                            \
            int ch = w * 2 + cc;              /* 1KB chunk = 16 Vt-rows */          \
            int d = ch * 16 + (l >> 2);                                             \
            int c = (l & 3) ^ (d & 3);                                              \
            gll16(&qth[(size_t)d * SEQ + (jb) + c * 8], &Vt[buf][(size_t)ch * 512]); \
        }                                                                           \
    }

    // prologue: tiles 0 and 1 in flight (8 gll16/wave after the 16 qf loads)
    STAGE(0, jb0);
    STAGE(1, jb0 + 32);

    f32x16 Oacc[8];  // O^T[d][q]: lane q = l31; reg r of tile dt: d = dt*32+(r&3)+8*(r>>2)+4*hi
#pragma unroll
    for (int i = 0; i < 8; ++i) Oacc[i] = (f32x16)(0.f);
    float mrow = -INFINITY, lrow = 0.f;   // for q-row qrow (dup across lane pair)

    for (int t = 0; t < NT; ++t) {
        const int cur = t & 1;

        // ---- B1: stage(t) landed (and, at t=0, qf); stage(t+1) stays in flight ----
        __builtin_amdgcn_sched_barrier(0);
        if (t < NT - 1) { asm volatile("s_waitcnt vmcnt(4)" ::: "memory"); }
        else            { asm volatile("s_waitcnt vmcnt(0)" ::: "memory"); }
        __builtin_amdgcn_s_barrier();
        __builtin_amdgcn_sched_barrier(0);

        // ---- S^T = K @ Q^T : D[j][q], lane holds q=l31, 16 j's ----
        const unsigned short* Kb = &Ks[cur][0];
        f32x16 sacc = (f32x16)(0.f);
        __builtin_amdgcn_s_setprio(1);
#pragma unroll
        for (int s = 0; s < 16; ++s) {
            int c = s * 2 + hi;
            int st = (c & 24) | ((c & 7) ^ (l31 & 7));
            bf16x8 kf = *(const bf16x8*)&Kb[l31 * 256 + st * 8];   // A row j=l31
            sacc = mfma32(kf, qf[s], sacc);
        }
        __builtin_amdgcn_s_setprio(0);

        // ---- lane-local online softmax, defer-rescale THR=8 ----
        float mx = sacc[0];
#pragma unroll
        for (int r = 1; r < 16; ++r) mx = fmaxf(mx, sacc[r]);
        mx = fmaxf(mx, __shfl_xor(mx, 32, 64));

        const bool needr = !__all(mx <= mrow + 8.f);
        if (needr) {
            float mn = fmaxf(mrow, mx);
            float alpha = __expf(mrow - mn);
            mrow = mn;
            lrow *= alpha;
#pragma unroll
            for (int dt = 0; dt < 8; ++dt) Oacc[dt] *= alpha;   // lane-local (col=q)
        }

        float rsum = 0.f;
#pragma unroll
        for (int r = 0; r < 16; ++r) {
            float p = __expf(sacc[r] - mrow);
            rsum += p;
            sacc[r] = p;
        }
        rsum += __shfl_xor(rsum, 32, 64);
        lrow += rsum;

        // ---- P -> B-frags in registers (pack + cross-half shuffle) ----
        // reg r holds j = (r&3) + 8*(r>>2) + 4*hi (within this 32-j tile)
        unsigned pk8[8];
#pragma unroll
        for (int m = 0; m < 8; ++m)
            pk8[m] = (unsigned)f2b(sacc[2 * m]) | ((unsigned)f2b(sacc[2 * m + 1]) << 16);
        bf16x8 pbf[2];
#pragma unroll
        for (int js = 0; js < 2; ++js) {
            unsigned a0 = pk8[js * 4 + 0], a1 = pk8[js * 4 + 1];
            unsigned b0 = pk8[js * 4 + 2], b1 = pk8[js * 4 + 3];
            unsigned sa0 = (unsigned)__shfl_xor((int)a0, 32, 64);
            unsigned sa1 = (unsigned)__shfl_xor((int)a1, 32, 64);
            unsigned sb0 = (unsigned)__shfl_xor((int)b0, 32, 64);
            unsigned sb1 = (unsigned)__shfl_xor((int)b1, 32, 64);
            union { unsigned u[4]; bf16x8 v; } U;
            U.u[0] = hi ? sb0 : a0;   // k-elems {8hi+0, 8hi+1}
            U.u[1] = hi ? sb1 : a1;   // {8hi+2, 8hi+3}
            U.u[2] = hi ? b0 : sa0;   // {8hi+4, 8hi+5}
            U.u[3] = hi ? b1 : sa1;   // {8hi+6, 8hi+7}
            pbf[js] = U.v;
        }

        // ---- O^T += V^T @ P^T : 8 d-tiles x 2 j-steps ----
        const unsigned short* Vb = &Vt[cur][0];
        __builtin_amdgcn_s_setprio(1);
#pragma unroll
        for (int dt = 0; dt < 8; ++dt) {
            int d = dt * 32 + l31;
#pragma unroll
            for (int js = 0; js < 2; ++js) {
                int c = js * 2 + hi;
                int st = c ^ (d & 3);
                bf16x8 vf = *(const bf16x8*)&Vb[d * 32 + st * 8];  // A row m=d
                Oacc[dt] = mfma32(vf, pbf[js], Oacc[dt]);
            }
        }
        __builtin_amdgcn_s_setprio(0);

        // ---- B2: all waves done with buf[cur] -> restage it for t+2 ----
        __builtin_amdgcn_sched_barrier(0);
        __builtin_amdgcn_s_barrier();
        __builtin_amdgcn_sched_barrier(0);
        if (t + 2 < NT) STAGE(cur, jb0 + (t + 2) * 32);
        __builtin_amdgcn_sched_barrier(0);
    }
#undef STAGE

    // ---- epilogue: unnormalized partial O (bf16) + per-row (m, l) ----
    unsigned short* po = (tt == 0) ? p0 : (tt == 1) ? p1 : p2;
#pragma unroll
    for (int dt = 0; dt < 8; ++dt)
#pragma unroll
        for (int k = 0; k < 4; ++k) {
            int d = dt * 32 + k * 8 + hi * 4;
            short4v o;
#pragma unroll
            for (int i = 0; i < 4; ++i) o[i] = (short)f2b(Oacc[dt][4 * k + i]);
            *(short4v*)&po[(size_t)qrow * (NHEADS * DHEAD) + h * DHEAD + d] = o;
        }
    if (hi == 0) {
        float* mlq = ml + ((size_t)(tt * NHEADS + h) * SEQ + qrow) * 2;
        mlq[0] = mrow; mlq[1] = lrow;
    }
}

// ---------------------------------------------------------------------------
// K2b: combine the three key-thirds:
// out = sum_i e_i*acc_i / sum_i e_i*l_i,  e_i = exp(m_i - max_i m_i)
// ---------------------------------------------------------------------------
__global__ __launch_bounds__(256)
void combine_kernel(const unsigned short* __restrict__ pa,
                    const unsigned short* __restrict__ pb,
                    const unsigned short* __restrict__ pc,
                    const float* __restrict__ ml,
                    unsigned short* __restrict__ zc) {
    size_t t = (size_t)blockIdx.x * 256 + threadIdx.x;
    size_t f = t * 8;
    int q = (int)(f >> 10);
    int h = (int)((f >> 8) & 3);
    const float* ml0 = ml + ((size_t)(0 * NHEADS + h) * SEQ + q) * 2;
    const float* ml1 = ml + ((size_t)(1 * NHEADS + h) * SEQ + q) * 2;
    const float* ml2 = ml + ((size_t)(2 * NHEADS + h) * SEQ + q) * 2;
    float m0 = ml0[0], l0 = ml0[1];
    float m1 = ml1[0], l1 = ml1[1];
    float m2 = ml2[0], l2 = ml2[1];
    float M = fmaxf(fmaxf(m0, m1), m2);
    float e0 = __expf(m0 - M), e1 = __expf(m1 - M), e2 = __expf(m2 - M);
    float inv = 1.f / (e0 * l0 + e1 * l1 + e2 * l2);
    e0 *= inv; e1 *= inv; e2 *= inv;
    short8v a = *(const short8v*)(pa + f);
    short8v b = *(const short8v*)(pb + f);
    short8v c = *(const short8v*)(pc + f);
    short8v o;
#pragma unroll
    for (int e = 0; e < 8; ++e)
        o[e] = (short)f2b(e0 * b2f((unsigned short)a[e]) +
                          e1 * b2f((unsigned short)b[e]) +
                          e2 * b2f((unsigned short)c[e]));
    *(short8v*)(zc + f) = o;
}

// ---------------------------------------------------------------------------
// K3: out = zc @ lin_w^T + lin_b  (fp32 out + bias)
// ---------------------------------------------------------------------------
__global__ __launch_bounds__(256)
void out_gemm_kernel(const unsigned short* __restrict__ A,
                     const unsigned short* __restrict__ B,
                     const float* __restrict__ lb, float* __restrict__ out) {
    __shared__ unsigned short As[128 * 64];
    __shared__ unsigned short Bs[128 * 64];
    const int tid = threadIdx.x, w = tid >> 6, l = tid & 63;
    const int g = l >> 4, r16 = l & 15;
    const int m0 = blockIdx.x * 128, n0 = blockIdx.y * 128;
    const int wm = (w >> 1) * 64, wn = (w & 1) * 64;

    f32x4 acc[4][4];
#pragma unroll
    for (int mr = 0; mr < 4; ++mr)
#pragma unroll
        for (int nr = 0; nr < 4; ++nr) acc[mr][nr] = (f32x4){0.f, 0.f, 0.f, 0.f};

    for (int kb = 0; kb < DIM; kb += 64) {
        __syncthreads();
#pragma unroll
        for (int cc = 0; cc < 4; ++cc) {
            int row = w * 32 + cc * 8 + (l >> 3);
            int c = (l & 7) ^ (row & 7);
            gll16(&A[(size_t)(m0 + row) * DIM + kb + c * 8], &As[(size_t)(w * 32 + cc * 8) * 64]);
            gll16(&B[(size_t)(n0 + row) * DIM + kb + c * 8], &Bs[(size_t)(w * 32 + cc * 8) * 64]);
        }
        __syncthreads();
#pragma unroll
        for (int s = 0; s < 2; ++s) {
            bf16x8 af[4], bf[4];
#pragma unroll
            for (int mr = 0; mr < 4; ++mr) {
                int row = wm + mr * 16 + r16;
                int st = (s * 4 + g) ^ (row & 7);
                af[mr] = *(const bf16x8*)&As[row * 64 + st * 8];
            }
#pragma unroll
            for (int nr = 0; nr < 4; ++nr) {
                int row = wn + nr * 16 + r16;
                int st = (s * 4 + g) ^ (row & 7);
                bf[nr] = *(const bf16x8*)&Bs[row * 64 + st * 8];
            }
#pragma unroll
            for (int mr = 0; mr < 4; ++mr)
#pragma unroll
                for (int nr = 0; nr < 4; ++nr)
                    acc[mr][nr] = mfma16(af[mr], bf[nr], acc[mr][nr]);
        }
    }
#pragma unroll
    for (int mr = 0; mr < 4; ++mr)
#pragma unroll
        for (int nr = 0; nr < 4; ++nr) {
            int n = n0 + wn + nr * 16 + r16;
            float bv = lb[n];
#pragma unroll
            for (int r = 0; r < 4; ++r) {
                int m = m0 + wm + mr * 16 + g * 4 + r;
                out[(size_t)m * DIM + n] = acc[mr][nr][r] + bv;
            }
        }
}

// ---------------------------------------------------------------------------
extern "C" void kernel_launch(void* const* d_in, const int* in_sizes, int n_in,
                              void* d_out, int out_size, void* d_ws, size_t ws_size,
                              hipStream_t stream) {
    const float* x  = (const float*)d_in[0];   // [4096,1024]
    const float* Wq = (const float*)d_in[1];   // [4,1024,256]
    const float* lw = (const float*)d_in[2];   // [1024,1024]
    const float* lb = (const float*)d_in[3];   // [1024]
    float* out = (float*)d_out;                // [4096,1024] fp32

    char* wsb = (char*)d_ws;
    unsigned short* qkvb = (unsigned short*)(wsb);                      // [0,8)MB  [4][4096][256]
    unsigned short* p0   = (unsigned short*)(wsb + ((size_t)8 << 20));  // [8,16)   partial tt=0 -> zc
    unsigned short* xb   = (unsigned short*)(wsb + ((size_t)16 << 20)); // [16,24)  x bf16 -> p1
    unsigned short* p1   = xb;                                          //          (xb dead post qkv_gemm)
    unsigned short* WqT  = (unsigned short*)(wsb + ((size_t)24 << 20)); // [24,26)  WqT bf16 -> ml
    float*          ml   = (float*)(wsb + ((size_t)24 << 20));          //          (WqT dead post qkv_gemm)
    unsigned short* lwb  = (unsigned short*)(wsb + ((size_t)26 << 20)); // [26,28)  lin_w bf16
    // d_out doubles as scratch until out_gemm (which overwrites it last):
    unsigned short* qkvT = (unsigned short*)d_out;                          // d_out[0,8)MB
    unsigned short* p2   = (unsigned short*)d_out + ((size_t)4 << 20);      // d_out[8,16)MB

    conv_kernel<<<4096, 256, 0, stream>>>(x, xb, (SEQ * DIM) / 4);
    conv_kernel<<<1024, 256, 0, stream>>>(lw, lwb, (DIM * DIM) / 4);
    wqt_kernel<<<dim3(16, 4, 4), 256, 0, stream>>>(Wq, WqT);
    qkv_gemm_kernel<<<dim3(SEQ / 128, DIM / 128), 256, 0, stream>>>(xb, WqT, qkvb);
    qkvt_kernel<<<dim3(64, 4, 4), 256, 0, stream>>>(qkvb, qkvT);
    attn_kernel<<<192, 512, 0, stream>>>(qkvb, qkvT, p0, p1, p2, ml);
    combine_kernel<<<(SEQ * DIM / 8) / 256, 256, 0, stream>>>(p0, p1, p2, ml, p0);
    out_gemm_kernel<<<dim3(SEQ / 128, DIM / 128), 256, 0, stream>>>(p0, lwb, lb, out);
}

// Round 10
// 170.243 us; speedup vs baseline: 1.1075x; 1.1075x over previous
//
#include <hip/hip_runtime.h>
#include <math.h>

#define SEQ 4096
#define DIM 1024
#define DHEAD 256
#define NHEADS 4

typedef __attribute__((ext_vector_type(8))) short bf16x8;
typedef __attribute__((ext_vector_type(4))) float f32x4;
typedef __attribute__((ext_vector_type(4))) short short4v;
typedef __attribute__((ext_vector_type(8))) short short8v;

// fp32 -> bf16 round-to-nearest-even, as raw ushort bits
__device__ __forceinline__ unsigned short f2b(float f) {
    union { float f; unsigned u; } v; v.f = f;
    unsigned r = v.u + 0x7FFFu + ((v.u >> 16) & 1u);
    return (unsigned short)(r >> 16);
}
__device__ __forceinline__ float b2f(unsigned short u) {
    union { unsigned u; float f; } v; v.u = ((unsigned)u) << 16;
    return v.f;
}

// async global->LDS, 16B per lane; lds = wave-uniform base, g is per-lane
__device__ __forceinline__ void gll16(const void* g, void* lds) {
    __builtin_amdgcn_global_load_lds(
        (const __attribute__((address_space(1))) unsigned*)g,
        (__attribute__((address_space(3))) unsigned*)lds, 16, 0, 0);
}

__device__ __forceinline__ f32x4 mfma16(bf16x8 a, bf16x8 b, f32x4 c) {
    return __builtin_amdgcn_mfma_f32_16x16x32_bf16(a, b, c, 0, 0, 0);
}

// ---------------------------------------------------------------------------
// convert fp32 -> bf16, n4 float4's
// ---------------------------------------------------------------------------
__global__ __launch_bounds__(256)
void conv_kernel(const float* __restrict__ in, unsigned short* __restrict__ out, int n4) {
    int i = blockIdx.x * 256 + threadIdx.x;
    if (i >= n4) return;
    float4 v = ((const float4*)in)[i];
    short4v o;
    o[0] = (short)f2b(v.x); o[1] = (short)f2b(v.y);
    o[2] = (short)f2b(v.z); o[3] = (short)f2b(v.w);
    *(short4v*)(out + (size_t)i * 4) = o;
}

// ---------------------------------------------------------------------------
// Wq [4][1024][256] fp32 -> WqT [4][256][1024] bf16
// ---------------------------------------------------------------------------
__global__ __launch_bounds__(256)
void wqt_kernel(const float* __restrict__ Wq, unsigned short* __restrict__ WqT) {
    __shared__ unsigned short T[64][72];
    const int tid = threadIdx.x;
    const int h = blockIdx.z;
    const int d0 = blockIdx.x * 64, c0 = blockIdx.y * 64;
#pragma unroll
    for (int it = 0; it < 4; ++it) {
        int f = tid + 256 * it;
        int row = f >> 4, cg = f & 15;
        float4 v = *(const float4*)&Wq[((size_t)(h * DIM + d0 + row)) * DHEAD + c0 + cg * 4];
        T[row][cg * 4 + 0] = f2b(v.x); T[row][cg * 4 + 1] = f2b(v.y);
        T[row][cg * 4 + 2] = f2b(v.z); T[row][cg * 4 + 3] = f2b(v.w);
    }
    __syncthreads();
#pragma unroll
    for (int it = 0; it < 2; ++it) {
        int f = tid + 256 * it;
        int cl = f >> 3, dg = f & 7;
        short8v o;
#pragma unroll
        for (int e = 0; e < 8; ++e) o[e] = (short)T[dg * 8 + e][cl];
        *(short8v*)&WqT[((size_t)(h * DHEAD + c0 + cl)) * DIM + d0 + dg * 8] = o;
    }
}

// ---------------------------------------------------------------------------
// qkv [4][4096][256] bf16 -> qkvT [4][256][4096] bf16
// ---------------------------------------------------------------------------
__global__ __launch_bounds__(256)
void qkvt_kernel(const unsigned short* __restrict__ qkv, unsigned short* __restrict__ qkvT) {
    __shared__ unsigned short T[64][72];
    const int tid = threadIdx.x;
    const int h = blockIdx.z;
    const int r0 = blockIdx.x * 64, c0 = blockIdx.y * 64;
#pragma unroll
    for (int it = 0; it < 2; ++it) {
        int f = tid + 256 * it;
        int row = f >> 3, cg = f & 7;
        short8v v = *(const short8v*)&qkv[((size_t)h * SEQ + r0 + row) * DHEAD + c0 + cg * 8];
#pragma unroll
        for (int e = 0; e < 8; ++e) T[row][cg * 8 + e] = (unsigned short)v[e];
    }
    __syncthreads();
#pragma unroll
    for (int it = 0; it < 2; ++it) {
        int f = tid + 256 * it;
        int cl = f >> 3, rg = f & 7;
        short8v o;
#pragma unroll
        for (int e = 0; e < 8; ++e) o[e] = (short)T[rg * 8 + e][cl];
        *(short8v*)&qkvT[((size_t)h * DHEAD + c0 + cl) * SEQ + r0 + rg * 8] = o;
    }
}

// ---------------------------------------------------------------------------
// K1: qkv = x @ Wq  (bf16 MFMA, BM=BN=128, BK=64, out: qkv bf16 [4][4096][256])
// ---------------------------------------------------------------------------
__global__ __launch_bounds__(256)
void qkv_gemm_kernel(const unsigned short* __restrict__ A,
                     const unsigned short* __restrict__ B,
                     unsigned short* __restrict__ qkv) {
    __shared__ unsigned short As[128 * 64];
    __shared__ unsigned short Bs[128 * 64];
    const int tid = threadIdx.x, w = tid >> 6, l = tid & 63;
    const int g = l >> 4, r16 = l & 15;
    const int m0 = blockIdx.x * 128, n0 = blockIdx.y * 128;
    const int wm = (w >> 1) * 64, wn = (w & 1) * 64;

    f32x4 acc[4][4];
#pragma unroll
    for (int mr = 0; mr < 4; ++mr)
#pragma unroll
        for (int nr = 0; nr < 4; ++nr) acc[mr][nr] = (f32x4){0.f, 0.f, 0.f, 0.f};

    for (int kb = 0; kb < DIM; kb += 64) {
        __syncthreads();
#pragma unroll
        for (int cc = 0; cc < 4; ++cc) {
            int row = w * 32 + cc * 8 + (l >> 3);
            int c = (l & 7) ^ (row & 7);
            gll16(&A[(size_t)(m0 + row) * DIM + kb + c * 8], &As[(size_t)(w * 32 + cc * 8) * 64]);
            gll16(&B[(size_t)(n0 + row) * DIM + kb + c * 8], &Bs[(size_t)(w * 32 + cc * 8) * 64]);
        }
        __syncthreads();
#pragma unroll
        for (int s = 0; s < 2; ++s) {
            bf16x8 af[4], bf[4];
#pragma unroll
            for (int mr = 0; mr < 4; ++mr) {
                int row = wm + mr * 16 + r16;
                int st = (s * 4 + g) ^ (row & 7);
                af[mr] = *(const bf16x8*)&As[row * 64 + st * 8];
            }
#pragma unroll
            for (int nr = 0; nr < 4; ++nr) {
                int row = wn + nr * 16 + r16;
                int st = (s * 4 + g) ^ (row & 7);
                bf[nr] = *(const bf16x8*)&Bs[row * 64 + st * 8];
            }
#pragma unroll
            for (int mr = 0; mr < 4; ++mr)
#pragma unroll
                for (int nr = 0; nr < 4; ++nr)
                    acc[mr][nr] = mfma16(af[mr], bf[nr], acc[mr][nr]);
        }
    }
#pragma unroll
    for (int mr = 0; mr < 4; ++mr)
#pragma unroll
        for (int nr = 0; nr < 4; ++nr) {
            int n = n0 + wn + nr * 16 + r16;
            int h = n >> 8, c = n & 255;
#pragma unroll
            for (int r = 0; r < 4; ++r) {
                int m = m0 + wm + mr * 16 + g * 4 + r;
                qkv[((size_t)h * SEQ + m) * DHEAD + c] = f2b(acc[mr][nr][r]);
            }
        }
}

// ---------------------------------------------------------------------------
// K2: MFMA flash attention. 512 thr / 8 waves, 1 block/CU (144KB LDS).
// Wave owns 32 q-rows (2 x 16-row sub-tiles) -> every af/bv LDS read feeds
// TWO MFMAs (halves LDS bytes per FLOP vs R8). QBLK=256.
// grid 16*4*NSPLIT: combo = bid & (4*NSPLIT-1) -> (h, hf); qb = high bits.
// R8's proven pipeline: B1 = counted vmcnt + s_barrier; stage(t+2) after B2.
// Ps: shared 16-row slot per wave, two passes (write/fence/read per qs).
// ---------------------------------------------------------------------------
template<int NSPLIT>
__global__ __launch_bounds__(512, 2)
void attn_kernel(const unsigned short* __restrict__ qkv,
                 const unsigned short* __restrict__ qkvT,
                 unsigned short* __restrict__ p0,
                 unsigned short* __restrict__ p1,
                 unsigned short* __restrict__ p2,
                 unsigned short* __restrict__ p3,
                 float* __restrict__ ml) {
    __shared__ unsigned short Ks[2][64 * 256];  // 2x32KB, row j: st=(c&24)|((c&7)^(j&7))
    __shared__ unsigned short Vt[2][256 * 64];  // 2x32KB, row d: st=c^(d&7)
    __shared__ unsigned short Ps[8][16 * 64];   // 8x2KB,  row q: st=(j>>3)^(q&7)

    const int tid = threadIdx.x, w = tid >> 6, l = tid & 63;
    const int g = l >> 4, r16 = l & 15;
    const int bid = blockIdx.x;
    constexpr int CSH = (NSPLIT == 4) ? 4 : 3;
    const int combo = bid & ((1 << CSH) - 1);
    const int h = combo >> ((NSPLIT == 4) ? 2 : 1);
    const int hf = combo & (NSPLIT - 1);
    const int qb = bid >> CSH;                   // q-block of 256 rows
    const unsigned short* __restrict__ qh = qkv + (size_t)h * SEQ * DHEAD;
    const unsigned short* __restrict__ qth = qkvT + (size_t)h * DHEAD * SEQ;
    const int jb0 = hf * (SEQ / NSPLIT);
    const int NT = (SEQ / NSPLIT) / 64;

    // Q fragments (B-operand): q-row = qb*256 + w*32 + qs*16 + r16, d = 32s+8g+e
    bf16x8 qf[2][8];
#pragma unroll
    for (int qs = 0; qs < 2; ++qs) {
        const unsigned short* qrow =
            qh + (size_t)(qb * 256 + w * 32 + qs * 16 + r16) * DHEAD + g * 8;
#pragma unroll
        for (int s = 0; s < 8; ++s) qf[qs][s] = *(const bf16x8*)(qrow + s * 32);
    }

#define STAGEK(buf, jb)                                                             \
    {                                                                               \
        _Pragma("unroll")                                                           \
        for (int cc = 0; cc < 4; ++cc) {                                            \
            int ch = w * 4 + cc;              /* 1KB chunk = 2 K-rows */            \
            int j = ch * 2 + (l >> 5);                                              \
            int cp = l & 31;                                                        \
            int c = (cp & 24) | ((cp & 7) ^ (j & 7));                               \
            gll16(&qh[(size_t)((jb) + j) * DHEAD + c * 8], &Ks[buf][(size_t)ch * 512]); \
        }                                                                           \
    }
#define STAGEV(buf, jb)                                                             \
    {                                                                               \
        _Pragma("unroll")                                                           \
        for (int cc = 0; cc < 4; ++cc) {                                            \
            int ch = w * 4 + cc;              /* 1KB chunk = 8 Vt-rows */           \
            int d = ch * 8 + (l >> 3);                                              \
            int c = (l & 7) ^ (d & 7);                                              \
            gll16(&qth[(size_t)d * SEQ + (jb) + c * 8], &Vt[buf][(size_t)ch * 512]); \
        }                                                                           \
    }

    // prologue: tiles 0 and 1 in flight
    STAGEK(0, jb0); STAGEV(0, jb0);
    STAGEK(1, jb0 + 64); STAGEV(1, jb0 + 64);

    f32x4 Oacc[2][16];  // [qs][dt]: lane holds O[q=qs*16+4g+r][d=dt*16+r16]
#pragma unroll
    for (int qs = 0; qs < 2; ++qs)
#pragma unroll
        for (int i = 0; i < 16; ++i) Oacc[qs][i] = (f32x4){0.f, 0.f, 0.f, 0.f};
    float mrow[2] = {-INFINITY, -INFINITY}, lrow[2] = {0.f, 0.f};  // q = qs*16+r16

    for (int t = 0; t < NT; ++t) {
        const int cur = t & 1;

        // ---- B1: stage(t) landed; stage(t+1) stays in flight ----
        __builtin_amdgcn_sched_barrier(0);
        if (t < NT - 1) { asm volatile("s_waitcnt vmcnt(8)" ::: "memory"); }
        else            { asm volatile("s_waitcnt vmcnt(0)" ::: "memory"); }
        __builtin_amdgcn_s_barrier();
        __builtin_amdgcn_sched_barrier(0);

        // ---- S^T = K @ Q^T : each af read feeds BOTH qs sub-tiles ----
        const unsigned short* Kb = &Ks[cur][0];
        f32x4 sacc[2][4];
#pragma unroll
        for (int qs = 0; qs < 2; ++qs)
#pragma unroll
            for (int jt = 0; jt < 4; ++jt) sacc[qs][jt] = (f32x4){0.f, 0.f, 0.f, 0.f};
        __builtin_amdgcn_s_setprio(1);
#pragma unroll
        for (int s = 0; s < 8; ++s)
#pragma unroll
            for (int jt = 0; jt < 4; ++jt) {
                int j = jt * 16 + r16;
                int c = s * 4 + g;
                int st = (c & 24) | ((c & 7) ^ (j & 7));
                bf16x8 af = *(const bf16x8*)&Kb[j * 256 + st * 8];
                sacc[0][jt] = mfma16(af, qf[0][s], sacc[0][jt]);
                sacc[1][jt] = mfma16(af, qf[1][s], sacc[1][jt]);
            }
        __builtin_amdgcn_s_setprio(0);

        // ---- per-qs: in-register softmax + Ps round-trip (shared slot) ----
        bf16x8 pa[2][2];
#pragma unroll
        for (int qs = 0; qs < 2; ++qs) {
            float mx = sacc[qs][0][0];
#pragma unroll
            for (int jt = 0; jt < 4; ++jt)
#pragma unroll
                for (int r = 0; r < 4; ++r) mx = fmaxf(mx, sacc[qs][jt][r]);
            mx = fmaxf(mx, __shfl_xor(mx, 16, 64));
            mx = fmaxf(mx, __shfl_xor(mx, 32, 64));

            const bool needr = !__all(mx <= mrow[qs] + 8.f);
            float alpha = 1.f;
            if (needr) {
                float mn = fmaxf(mrow[qs], mx);
                alpha = __expf(mrow[qs] - mn);
                mrow[qs] = mn;
            }

            float rsum = 0.f;
            short4v pf[4];
#pragma unroll
            for (int jt = 0; jt < 4; ++jt)
#pragma unroll
                for (int r = 0; r < 4; ++r) {
                    float p = __expf(sacc[qs][jt][r] - mrow[qs]);
                    rsum += p;
                    pf[jt][r] = (short)f2b(p);
                }
            rsum += __shfl_xor(rsum, 16, 64);
            rsum += __shfl_xor(rsum, 32, 64);
            lrow[qs] = lrow[qs] * alpha + rsum;

            // write P(qs) into the wave's 16-row slot
#pragma unroll
            for (int jt = 0; jt < 4; ++jt) {
                int st = (2 * jt + (g >> 1)) ^ (r16 & 7);
                *(short4v*)&Ps[w][r16 * 64 + st * 8 + (g & 1) * 4] = pf[jt];
            }

            // O(qs) rescale while the writes drain
            if (needr) {
                float av[4];
#pragma unroll
                for (int r = 0; r < 4; ++r) av[r] = __shfl(alpha, 4 * g + r, 64);
#pragma unroll
                for (int dt = 0; dt < 16; ++dt)
#pragma unroll
                    for (int r = 0; r < 4; ++r) Oacc[qs][dt][r] *= av[r];
            }

            asm volatile("s_waitcnt lgkmcnt(0)" ::: "memory");
#pragma unroll
            for (int s2 = 0; s2 < 2; ++s2) {
                int st = (4 * s2 + g) ^ (r16 & 7);
                pa[qs][s2] = *(const bf16x8*)&Ps[w][r16 * 64 + st * 8];
            }
            asm volatile("s_waitcnt lgkmcnt(0)" ::: "memory");  // reads done before next pass overwrites
        }

        // ---- O += P @ V : each bv read feeds BOTH qs sub-tiles ----
        const unsigned short* Vb = &Vt[cur][0];
        __builtin_amdgcn_s_setprio(1);
#pragma unroll
        for (int dt = 0; dt < 16; ++dt) {
            int d = dt * 16 + r16;
#pragma unroll
            for (int s2 = 0; s2 < 2; ++s2) {
                int st = (4 * s2 + g) ^ (d & 7);
                bf16x8 bv = *(const bf16x8*)&Vb[d * 64 + st * 8];
                Oacc[0][dt] = mfma16(pa[0][s2], bv, Oacc[0][dt]);
                Oacc[1][dt] = mfma16(pa[1][s2], bv, Oacc[1][dt]);
            }
        }
        __builtin_amdgcn_s_setprio(0);

        // ---- B2: all waves done with buf[cur] -> restage it for t+2 ----
        __builtin_amdgcn_sched_barrier(0);
        __builtin_amdgcn_s_barrier();
        __builtin_amdgcn_sched_barrier(0);
        if (t + 2 < NT) {
            const int jb2 = jb0 + (t + 2) * 64;
            STAGEK(cur, jb2); STAGEV(cur, jb2);
        }
        __builtin_amdgcn_sched_barrier(0);
    }
#undef STAGEK
#undef STAGEV

    asm volatile("s_waitcnt vmcnt(0)" ::: "memory");

    // ---- epilogue: unnormalized partial O (bf16) + per-row (m, l) ----
    unsigned short* po = (hf == 0) ? p0 : (hf == 1) ? p1 : (hf == 2) ? p2 : p3;
#pragma unroll
    for (int qs = 0; qs < 2; ++qs)
#pragma unroll
        for (int dt = 0; dt < 16; ++dt) {
            int d = dt * 16 + r16;
#pragma unroll
            for (int r = 0; r < 4; ++r) {
                int q = qb * 256 + w * 32 + qs * 16 + 4 * g + r;
                po[(size_t)q * (NHEADS * DHEAD) + h * DHEAD + d] = f2b(Oacc[qs][dt][r]);
            }
        }
    if (g == 0) {
#pragma unroll
        for (int qs = 0; qs < 2; ++qs) {
            int q = qb * 256 + w * 32 + qs * 16 + r16;
            float* mlq = ml + ((size_t)(hf * NHEADS + h) * SEQ + q) * 2;
            mlq[0] = mrow[qs]; mlq[1] = lrow[qs];
        }
    }
}

// ---------------------------------------------------------------------------
// K2b: combine NSPLIT key-partials:
// out = sum_s e_s*acc_s / sum_s e_s*l_s,  e_s = exp(m_s - max_s m_s)
// ---------------------------------------------------------------------------
template<int NSPLIT>
__global__ __launch_bounds__(256)
void combine_kernel(const unsigned short* __restrict__ pA,
                    const unsigned short* __restrict__ pB,
                    const unsigned short* __restrict__ pC,
                    const unsigned short* __restrict__ pD,
                    const float* __restrict__ ml,
                    unsigned short* __restrict__ zc) {
    size_t t = (size_t)blockIdx.x * 256 + threadIdx.x;
    size_t f = t * 8;
    int q = (int)(f >> 10);
    int h = (int)((f >> 8) & 3);
    float mm[NSPLIT], lv[NSPLIT];
    float M = -INFINITY;
#pragma unroll
    for (int s = 0; s < NSPLIT; ++s) {
        const float* m = ml + ((size_t)(s * NHEADS + h) * SEQ + q) * 2;
        mm[s] = m[0]; lv[s] = m[1];
        M = fmaxf(M, mm[s]);
    }
    float es[NSPLIT], den = 0.f;
#pragma unroll
    for (int s = 0; s < NSPLIT; ++s) { es[s] = __expf(mm[s] - M); den += es[s] * lv[s]; }
    float inv = 1.f / den;
    const unsigned short* ps[4] = {pA, pB, pC, pD};
    float acc[8] = {0.f, 0.f, 0.f, 0.f, 0.f, 0.f, 0.f, 0.f};
#pragma unroll
    for (int s = 0; s < NSPLIT; ++s) {
        short8v v = *(const short8v*)(ps[s] + f);
#pragma unroll
        for (int e = 0; e < 8; ++e) acc[e] += es[s] * b2f((unsigned short)v[e]);
    }
    short8v o;
#pragma unroll
    for (int e = 0; e < 8; ++e) o[e] = (short)f2b(acc[e] * inv);
    *(short8v*)(zc + f) = o;
}

// ---------------------------------------------------------------------------
// K3: out = zc @ lin_w^T + lin_b  (fp32 out + bias)
// ---------------------------------------------------------------------------
__global__ __launch_bounds__(256)
void out_gemm_kernel(const unsigned short* __restrict__ A,
                     const unsigned short* __restrict__ B,
                     const float* __restrict__ lb, float* __restrict__ out) {
    __shared__ unsigned short As[128 * 64];
    __shared__ unsigned short Bs[128 * 64];
    const int tid = threadIdx.x, w = tid >> 6, l = tid & 63;
    const int g = l >> 4, r16 = l & 15;
    const int m0 = blockIdx.x * 128, n0 = blockIdx.y * 128;
    const int wm = (w >> 1) * 64, wn = (w & 1) * 64;

    f32x4 acc[4][4];
#pragma unroll
    for (int mr = 0; mr < 4; ++mr)
#pragma unroll
        for (int nr = 0; nr < 4; ++nr) acc[mr][nr] = (f32x4){0.f, 0.f, 0.f, 0.f};

    for (int kb = 0; kb < DIM; kb += 64) {
        __syncthreads();
#pragma unroll
        for (int cc = 0; cc < 4; ++cc) {
            int row = w * 32 + cc * 8 + (l >> 3);
            int c = (l & 7) ^ (row & 7);
            gll16(&A[(size_t)(m0 + row) * DIM + kb + c * 8], &As[(size_t)(w * 32 + cc * 8) * 64]);
            gll16(&B[(size_t)(n0 + row) * DIM + kb + c * 8], &Bs[(size_t)(w * 32 + cc * 8) * 64]);
        }
        __syncthreads();
#pragma unroll
        for (int s = 0; s < 2; ++s) {
            bf16x8 af[4], bf[4];
#pragma unroll
            for (int mr = 0; mr < 4; ++mr) {
                int row = wm + mr * 16 + r16;
                int st = (s * 4 + g) ^ (row & 7);
                af[mr] = *(const bf16x8*)&As[row * 64 + st * 8];
            }
#pragma unroll
            for (int nr = 0; nr < 4; ++nr) {
                int row = wn + nr * 16 + r16;
                int st = (s * 4 + g) ^ (row & 7);
                bf[nr] = *(const bf16x8*)&Bs[row * 64 + st * 8];
            }
#pragma unroll
            for (int mr = 0; mr < 4; ++mr)
#pragma unroll
                for (int nr = 0; nr < 4; ++nr)
                    acc[mr][nr] = mfma16(af[mr], bf[nr], acc[mr][nr]);
        }
    }
#pragma unroll
    for (int mr = 0; mr < 4; ++mr)
#pragma unroll
        for (int nr = 0; nr < 4; ++nr) {
            int n = n0 + wn + nr * 16 + r16;
            float bv = lb[n];
#pragma unroll
            for (int r = 0; r < 4; ++r) {
                int m = m0 + wm + mr * 16 + g * 4 + r;
                out[(size_t)m * DIM + n] = acc[mr][nr][r] + bv;
            }
        }
}

// ---------------------------------------------------------------------------
extern "C" void kernel_launch(void* const* d_in, const int* in_sizes, int n_in,
                              void* d_out, int out_size, void* d_ws, size_t ws_size,
                              hipStream_t stream) {
    const float* x  = (const float*)d_in[0];   // [4096,1024]
    const float* Wq = (const float*)d_in[1];   // [4,1024,256]
    const float* lw = (const float*)d_in[2];   // [1024,1024]
    const float* lb = (const float*)d_in[3];   // [1024]
    float* out = (float*)d_out;                // [4096,1024] fp32

    char* wsb = (char*)d_ws;
    unsigned short* qkvb = (unsigned short*)(wsb);                      // [0,8)MB  [4][4096][256]
    unsigned short* p0   = (unsigned short*)(wsb + ((size_t)8 << 20));  // [8,16)   partial 0 -> zc
    unsigned short* xb   = (unsigned short*)(wsb + ((size_t)16 << 20)); // [16,24)  x bf16 -> p1
    unsigned short* p1   = xb;                                          //          (xb dead post qkv_gemm)
    unsigned short* WqT  = (unsigned short*)(wsb + ((size_t)24 << 20)); // [24,26)  WqT bf16 -> ml
    float*          ml   = (float*)(wsb + ((size_t)24 << 20));          //          (WqT dead post qkv_gemm)
    unsigned short* lwb  = (unsigned short*)(wsb + ((size_t)26 << 20)); // [26,28)  lin_w bf16
    unsigned short* p3   = (unsigned short*)(wsb + ((size_t)28 << 20)); // [28,36)  partial 3 (if ws fits)
    // d_out doubles as scratch until out_gemm (which runs last):
    unsigned short* qkvT = (unsigned short*)d_out;                          // d_out[0,8)MB
    unsigned short* p2   = (unsigned short*)d_out + ((size_t)4 << 20);      // d_out[8,16)MB

    conv_kernel<<<4096, 256, 0, stream>>>(x, xb, (SEQ * DIM) / 4);
    conv_kernel<<<1024, 256, 0, stream>>>(lw, lwb, (DIM * DIM) / 4);
    wqt_kernel<<<dim3(16, 4, 4), 256, 0, stream>>>(Wq, WqT);
    qkv_gemm_kernel<<<dim3(SEQ / 128, DIM / 128), 256, 0, stream>>>(xb, WqT, qkvb);
    qkvt_kernel<<<dim3(64, 4, 4), 256, 0, stream>>>(qkvb, qkvT);

    if (ws_size >= ((size_t)36 << 20)) {
        attn_kernel<4><<<256, 512, 0, stream>>>(qkvb, qkvT, p0, p1, p2, p3, ml);
        combine_kernel<4><<<(SEQ * DIM / 8) / 256, 256, 0, stream>>>(p0, p1, p2, p3, ml, p0);
    } else {
        attn_kernel<2><<<128, 512, 0, stream>>>(qkvb, qkvT, p0, p1, p2, p3, ml);
        combine_kernel<2><<<(SEQ * DIM / 8) / 256, 256, 0, stream>>>(p0, p1, p2, p3, ml, p0);
    }
    out_gemm_kernel<<<dim3(SEQ / 128, DIM / 128), 256, 0, stream>>>(p0, lwb, lb, out);
}